// Round 1
// baseline (3123.364 us; speedup 1.0000x reference)
//
#include <hip/hip_runtime.h>

#define DEV __device__ __forceinline__

typedef _Float16 f16;
typedef _Float16 f16x8 __attribute__((ext_vector_type(8)));
typedef _Float16 f16x4 __attribute__((ext_vector_type(4)));
typedef float    f32x4 __attribute__((ext_vector_type(4)));

constexpr int Bn = 4, Tn = 512, Cn = 1024, Dn = 64, Fn = 4096, Ln = 6;
constexpr int TP = Tn + 2;   // padded token rows per batch (zero row at each end)

// ---------------- workspace layout (bytes) ----------------
constexpr size_t WQKV_OFF = 0;                                      // f16 [3072][1024]
constexpr size_t WO_OFF   = WQKV_OFF + (size_t)3072*1024*2;         // f16 [1024][1024]
constexpr size_t W1_OFF   = WO_OFF   + (size_t)1024*1024*2;         // f16 [4096][3][1024]
constexpr size_t W2_OFF   = W1_OFF   + (size_t)4096*3072*2;         // f16 [1024][3][4096]
constexpr size_t BQKV_OFF = W2_OFF   + (size_t)1024*12288*2;        // f32 [3072]
constexpr size_t H_OFF    = BQKV_OFF + (size_t)3072*4;              // f32 [2048][1024] residual
constexpr size_t HB1_OFF  = H_OFF    + (size_t)2048*1024*4;         // f16 [B][TP][1024] attn input
constexpr size_t HB2_OFF  = HB1_OFF  + (size_t)Bn*TP*Cn*2;          // f16 [B][TP][1024] conv1 input
constexpr size_t Y1B_OFF  = HB2_OFF  + (size_t)Bn*TP*Cn*2;          // f16 [B][TP][4096] conv2 input
constexpr size_t QB_OFF   = Y1B_OFF  + (size_t)Bn*TP*Fn*2;          // f16 [2048][1024] (pre-scaled q)
constexpr size_t KB_OFF   = QB_OFF   + (size_t)2048*1024*2;         // f16 [2048][1024]
constexpr size_t VT_OFF   = KB_OFF   + (size_t)2048*1024*2;         // f16 [B][1024][512] (v transposed)
constexpr size_t AO_OFF   = VT_OFF   + (size_t)2048*1024*2;         // f16 [2048][1024] attn out
constexpr size_t S_OFF    = AO_OFF   + (size_t)2048*1024*2;         // f32 [64][512][512] scores
constexpr size_t P_OFF    = S_OFF    + (size_t)64*512*512*4;        // f16 [64][512][512] probs
constexpr size_t RV_OFF   = P_OFF    + (size_t)64*512*512*2;        // f32 [64][512][64] rel-v add
constexpr size_t TMP_OFF  = RV_OFF   + (size_t)64*512*64*4;         // f32 [2048][1024] pre-LN

// ---------------- helpers ----------------
DEV void gload16(const void* g, void* l) {
  __builtin_amdgcn_global_load_lds(
      (const __attribute__((address_space(1))) unsigned int*)g,
      (__attribute__((address_space(3))) unsigned int*)l, 16, 0, 0);
}

DEV float wave_sum(float v) {
#pragma unroll
  for (int s = 32; s; s >>= 1) v += __shfl_xor(v, s, 64);
  return v;
}
DEV float wave_max(float v) {
#pragma unroll
  for (int s = 32; s; s >>= 1) v = fmaxf(v, __shfl_xor(v, s, 64));
  return v;
}

// ---------------- GEMM (modes) ----------------
// 0: QKV proj   A=HB1(pad)          B=WQKV         out q/k tokmajor, v -> VT
// 1: QK^T       A=QB(bh)            B=KB(bh)       out S fp32
// 2: PV         A=P(bh)             B=VT(bh)       out AO (+RV)
// 3: O proj     A=AO                B=WO           out TMP = gemm+bo+H
// 4: conv1      A=HB2(pad,shift)    B=W1           out Y1B = relu(gemm+b1)*mask
// 5: conv2      A=Y1B(pad,shift)    B=W2           out TMP = (gemm+b2)*mask+H
template <int MODE> struct GCfg {
  static constexpr int BN = (MODE == 2 || MODE == 3 || MODE == 5) ? 64 : 128;
  static constexpr int K  = (MODE == 0) ? 1024 : (MODE == 1) ? 64 : (MODE == 2) ? 512
                          : (MODE == 3) ? 1024 : (MODE == 4) ? 3072 : 12288;
};

template <int MODE> DEV size_t a_index(int r, int k, int bb, int hh, int bh) {
  if constexpr (MODE == 0) {            // HB1 padded token rows
    int b = r >> 9, t = r & 511;
    return ((size_t)(b * TP + 1 + t)) * Cn + k;
  } else if constexpr (MODE == 1) {     // QB
    return ((size_t)(bb * Tn + r)) * Cn + hh * Dn + k;
  } else if constexpr (MODE == 2) {     // P
    return ((size_t)bh * Tn + r) * (size_t)Tn + k;
  } else if constexpr (MODE == 3) {     // AO
    return (size_t)r * Cn + k;
  } else if constexpr (MODE == 4) {     // HB2 conv shift
    int b = r >> 9, t = r & 511;
    return ((size_t)(b * TP + t + (k >> 10))) * Cn + (k & 1023);
  } else {                              // Y1B conv shift
    int b = r >> 9, t = r & 511;
    return ((size_t)(b * TP + t + (k >> 12))) * Fn + (k & 4095);
  }
}
template <int MODE> DEV size_t b_index(int n, int k, int bb, int hh, int bh) {
  if constexpr (MODE == 0)      return (size_t)n * Cn + k;                       // WQKV
  else if constexpr (MODE == 1) return ((size_t)(bb * Tn + n)) * Cn + hh * Dn + k; // KB
  else if constexpr (MODE == 2) return ((size_t)(bh * Dn + n)) * Tn + k;         // VT
  else if constexpr (MODE == 3) return (size_t)n * Cn + k;                       // WO
  else if constexpr (MODE == 4) return (size_t)n * 3072 + k;                     // W1
  else                          return (size_t)n * 12288 + k;                    // W2
}

template <int MODE>
__global__ __launch_bounds__(256) void gemm_k(
    const f16* __restrict__ Ag, const f16* __restrict__ Bg,
    void* __restrict__ out0, void* __restrict__ out1, void* __restrict__ out2,
    const float* __restrict__ aux0, const float* __restrict__ aux1,
    const float* __restrict__ aux2)
{
  constexpr int BM = 128;
  constexpr int BN = GCfg<MODE>::BN;
  constexpr int K  = GCfg<MODE>::K;
  constexpr int NK = K / 32;
  constexpr int FM = 4;
  constexpr int FN = BN / 32;
  constexpr int AISS = 2;        // 128*32 f16 / (256 thr * 8)
  constexpr int BISS = BN / 64;

  __shared__ __align__(16) f16 As[BM * 32];
  __shared__ __align__(16) f16 Bs[BN * 32];

  const int tid = threadIdx.x;
  const int wv = tid >> 6, ln = tid & 63;
  const int wr = wv >> 1, wc = wv & 1;
  const int bn0 = blockIdx.x * BN;
  const int bm0 = blockIdx.y * BM;
  const int bh  = blockIdx.z;
  const int bb = bh >> 4, hh = bh & 15;

  f32x4 acc[FM][FN];
#pragma unroll
  for (int i = 0; i < FM; i++)
#pragma unroll
    for (int j = 0; j < FN; j++) acc[i][j] = (f32x4){0.f, 0.f, 0.f, 0.f};

  for (int kt = 0; kt < NK; ++kt) {
    const int k0 = kt * 32;
    __syncthreads();
#pragma unroll
    for (int q = 0; q < AISS; q++) {
      const int slot = q * 256 + tid;
      const int r = slot >> 2, cs = (slot & 3) * 8;
      const size_t gi = a_index<MODE>(bm0 + r, k0 + cs, bb, hh, bh);
      gload16(Ag + gi, &As[(size_t)(q * 256 + wv * 64) * 8]);
    }
#pragma unroll
    for (int q = 0; q < BISS; q++) {
      const int slot = q * 256 + tid;
      const int r = slot >> 2, cs = (slot & 3) * 8;
      const size_t gi = b_index<MODE>(bn0 + r, k0 + cs, bb, hh, bh);
      gload16(Bg + gi, &Bs[(size_t)(q * 256 + wv * 64) * 8]);
    }
    __syncthreads();

    f16x8 af[FM], bf[FN];
#pragma unroll
    for (int i = 0; i < FM; i++) {
      const int row = wr * 64 + i * 16 + (ln & 15);
      af[i] = *(const f16x8*)&As[row * 32 + (ln >> 4) * 8];
    }
#pragma unroll
    for (int j = 0; j < FN; j++) {
      const int col = wc * (BN / 2) + j * 16 + (ln & 15);
      bf[j] = *(const f16x8*)&Bs[col * 32 + (ln >> 4) * 8];
    }
#pragma unroll
    for (int i = 0; i < FM; i++)
#pragma unroll
      for (int j = 0; j < FN; j++)
        acc[i][j] = __builtin_amdgcn_mfma_f32_16x16x32_f16(af[i], bf[j], acc[i][j], 0, 0, 0);
  }

  const int r_base = bm0 + wr * 64 + ((ln >> 4) * 4);
  const int c_base = bn0 + wc * (BN / 2) + (ln & 15);
#pragma unroll
  for (int i = 0; i < FM; i++) {
#pragma unroll
    for (int j = 0; j < FN; j++) {
      const int c = c_base + j * 16;
#pragma unroll
      for (int jj = 0; jj < 4; jj++) {
        const int r = r_base + i * 16 + jj;
        float v = acc[i][j][jj];
        if constexpr (MODE == 0) {
          v += aux0[c];
          const int b = r >> 9, t = r & 511;
          if (c < 2048) {
            f16* dst = (c < 1024) ? (f16*)out0 : (f16*)out1;
            dst[(size_t)r * Cn + (c & 1023)] = (f16)v;
          } else {
            ((f16*)out2)[((size_t)b * Cn + (c - 2048)) * Tn + t] = (f16)v;
          }
        } else if constexpr (MODE == 1) {
          ((float*)out0)[((size_t)bh * Tn + r) * Tn + c] = v;
        } else if constexpr (MODE == 2) {
          v += aux0[((size_t)bh * Tn + r) * Dn + c];
          ((f16*)out0)[((size_t)(bb * Tn + r)) * Cn + hh * Dn + c] = (f16)v;
        } else if constexpr (MODE == 3) {
          v += aux0[c] + aux1[(size_t)r * Cn + c];
          ((float*)out0)[(size_t)r * Cn + c] = v;
        } else if constexpr (MODE == 4) {
          v += aux0[c];
          v = v > 0.f ? v : 0.f;
          const int b = r >> 9, t = r & 511;
          v *= aux1[b * Tn + t];
          ((f16*)out0)[((size_t)(b * TP + 1 + t)) * Fn + c] = (f16)v;
        } else {
          const int b = r >> 9, t = r & 511;
          v = (v + aux0[c]) * aux2[b * Tn + t] + aux1[(size_t)r * Cn + c];
          ((float*)out0)[(size_t)r * Cn + c] = v;
        }
      }
    }
  }
}

// ---------------- small kernels ----------------
__global__ void zero_pads(f16* hb1, f16* hb2, f16* y1b) {
  int i = blockIdx.x * 256 + threadIdx.x;
  if (i < Bn * 2 * Cn) {
    int b = i / (2 * Cn), rr = (i / Cn) & 1, c = i % Cn;
    size_t idx = ((size_t)(b * TP + rr * (TP - 1))) * Cn + c;
    hb1[idx] = (f16)0.f;
    hb2[idx] = (f16)0.f;
  }
  if (i < Bn * 2 * Fn) {
    int b = i / (2 * Fn), rr = (i / Fn) & 1, c = i % Fn;
    y1b[((size_t)(b * TP + rr * (TP - 1))) * Fn + c] = (f16)0.f;
  }
}

__global__ void prep_in(const float* __restrict__ x, const float* __restrict__ mask,
                        float* __restrict__ h, f16* __restrict__ hb1) {
  __shared__ float tile[32][33];
  int b = blockIdx.z;
  int c0 = blockIdx.y * 32, t0 = blockIdx.x * 32;
  int tx = threadIdx.x, ty = threadIdx.y;
  for (int i = ty; i < 32; i += 8)
    tile[i][tx] = x[((size_t)b * Cn + c0 + i) * Tn + t0 + tx];
  __syncthreads();
  for (int i = ty; i < 32; i += 8) {
    int t = t0 + i, c = c0 + tx;
    float v = tile[tx][i] * mask[b * Tn + t];
    h[((size_t)(b * Tn + t)) * Cn + c] = v;
    hb1[((size_t)(b * TP + 1 + t)) * Cn + c] = (f16)v;
  }
}

__global__ void finish_out(const float* __restrict__ h, const float* __restrict__ mask,
                           float* __restrict__ out) {
  __shared__ float tile[32][33];
  int b = blockIdx.z;
  int c0 = blockIdx.y * 32, t0 = blockIdx.x * 32;
  int tx = threadIdx.x, ty = threadIdx.y;
  for (int i = ty; i < 32; i += 8)
    tile[i][tx] = h[((size_t)(b * Tn + t0 + i)) * Cn + c0 + tx];
  __syncthreads();
  for (int i = ty; i < 32; i += 8)
    out[((size_t)b * Cn + c0 + i) * Tn + t0 + tx] = tile[tx][i] * mask[b * Tn + t0 + tx];
}

__global__ void conv_wqkv(const float* __restrict__ wq, const float* __restrict__ wk,
                          const float* __restrict__ wv, const float* __restrict__ bq_,
                          const float* __restrict__ bk_, const float* __restrict__ bv_,
                          f16* __restrict__ dst, float* __restrict__ bdst) {
  int i = blockIdx.x * 256 + threadIdx.x;   // < 3*1024*1024
  int n = i >> 10;
  float v;
  if (n < 1024)      v = wq[i] * 0.125f;                  // fold 1/sqrt(64) into q
  else if (n < 2048) v = wk[i - 1048576];
  else               v = wv[i - 2097152];
  dst[i] = (f16)v;
  if (i < 3072) {
    float bvv = (i < 1024) ? bq_[i] * 0.125f : (i < 2048 ? bk_[i - 1024] : bv_[i - 2048]);
    bdst[i] = bvv;
  }
}

__global__ void conv_cast(const float* __restrict__ src, f16* __restrict__ dst, int n) {
  int i = blockIdx.x * 256 + threadIdx.x;
  if (i < n) dst[i] = (f16)src[i];
}

// fw[f][c][kk] -> dst[f][kk][c]  (nc = 1<<sh channels)
__global__ void conv_w3(const float* __restrict__ src, f16* __restrict__ dst, int sh) {
  size_t i = (size_t)blockIdx.x * 256 + threadIdx.x;   // f*nc + c, total 4194304
  int c = (int)(i & (((size_t)1 << sh) - 1));
  size_t f = i >> sh;
  const float* s = src + i * 3;
  size_t base = ((f * 3) << sh) + c;
  dst[base]                      = (f16)s[0];
  dst[base + ((size_t)1 << sh)]  = (f16)s[1];
  dst[base + ((size_t)2 << sh)]  = (f16)s[2];
}

// softmax over S rows + rel-k band; writes P (f16)
__global__ __launch_bounds__(256) void softmax_k(
    const float* __restrict__ S, f16* __restrict__ P,
    const f16* __restrict__ QB, const float* __restrict__ relk,
    const float* __restrict__ mask)
{
  int row = blockIdx.x * 4 + (int)(threadIdx.x >> 6);   // bh*512 + t
  int ln = threadIdx.x & 63;
  int t = row & 511, bh = row >> 9;
  int b = bh >> 4, h = bh & 15;

  // 9 rel-k dots (q pre-scaled)
  float qv = (float)QB[((size_t)(b * Tn + t)) * Cn + h * Dn + ln];
  float rd[9];
#pragma unroll
  for (int j = 0; j < 9; j++) rd[j] = wave_sum(qv * relk[j * 64 + ln]);

  const float* srow = S + (size_t)row * Tn;
  float v[8];
  float mrow = mask[b * Tn + t];
  float mx = -1e30f;
#pragma unroll
  for (int q = 0; q < 2; q++) {
    f32x4 xx = *(const f32x4*)&srow[ln * 8 + q * 4];
#pragma unroll
    for (int e = 0; e < 4; e++) v[q * 4 + e] = xx[e];
  }
#pragma unroll
  for (int e = 0; e < 8; e++) {
    int s = ln * 8 + e;
    float val = v[e];
    int d = s - t;
    if (d >= -4 && d <= 4) val += rd[d + 4];
    if (mrow * mask[b * Tn + s] == 0.f) val = -1e4f;
    v[e] = val;
    mx = fmaxf(mx, val);
  }
  mx = wave_max(mx);
  float sum = 0.f;
#pragma unroll
  for (int e = 0; e < 8; e++) { v[e] = __expf(v[e] - mx); sum += v[e]; }
  sum = wave_sum(sum);
  float inv = 1.f / sum;
  f16x8 pv;
#pragma unroll
  for (int e = 0; e < 8; e++) pv[e] = (f16)(v[e] * inv);
  *(f16x8*)&P[(size_t)row * Tn + ln * 8] = pv;
}

// rel-v band: RV[bh,t,d] = sum_j P[t, t+j-4] * rv[j][d]
__global__ __launch_bounds__(256) void relv_k(const f16* __restrict__ P,
                                              const float* __restrict__ rv,
                                              float* __restrict__ RV) {
  int row = blockIdx.x * 4 + (int)(threadIdx.x >> 6);
  int d = threadIdx.x & 63;
  int t = row & 511;
  const f16* prow = P + (size_t)row * Tn;
  float acc = 0.f;
#pragma unroll
  for (int j = 0; j < 9; j++) {
    int s = t + j - 4;
    if (s >= 0 && s < Tn) acc += (float)prow[s] * rv[j * 64 + d];
  }
  RV[(size_t)row * Dn + d] = acc;
}

// LayerNorm over C; writes fp32 residual h + f16 GEMM input (WHICH==1: *mask for conv)
template <int WHICH>
__global__ __launch_bounds__(256) void ln_k(const float* __restrict__ tmp,
                                            const float* __restrict__ g,
                                            const float* __restrict__ bb_,
                                            const float* __restrict__ mask,
                                            float* __restrict__ h, f16* __restrict__ hb)
{
  int row = blockIdx.x * 4 + (int)(threadIdx.x >> 6);
  int ln = threadIdx.x & 63;
  const float* r = tmp + (size_t)row * Cn;
  f32x4 vv[4];
  float sum = 0.f, sq = 0.f;
#pragma unroll
  for (int q = 0; q < 4; q++) {
    vv[q] = *(const f32x4*)&r[q * 256 + ln * 4];
#pragma unroll
    for (int e = 0; e < 4; e++) { sum += vv[q][e]; sq += vv[q][e] * vv[q][e]; }
  }
  sum = wave_sum(sum);
  sq = wave_sum(sq);
  float mean = sum * (1.f / 1024.f);
  float var = sq * (1.f / 1024.f) - mean * mean;
  float rstd = rsqrtf(var + 1e-5f);
  int b = row >> 9, t = row & 511;
  float mk = (WHICH == 1) ? mask[b * Tn + t] : 1.f;
  float* hrow = h + (size_t)row * Cn;
  f16* hbrow = hb + ((size_t)(b * TP + 1 + t)) * Cn;
#pragma unroll
  for (int q = 0; q < 4; q++) {
    int c0 = q * 256 + ln * 4;
    f32x4 gv = *(const f32x4*)&g[c0];
    f32x4 bv = *(const f32x4*)&bb_[c0];
    f32x4 ov;
    f16x4 hv;
#pragma unroll
    for (int e = 0; e < 4; e++) {
      float y = (vv[q][e] - mean) * rstd * gv[e] + bv[e];
      ov[e] = y;
      hv[e] = (f16)(y * mk);
    }
    *(f32x4*)&hrow[c0] = ov;
    *(f16x4*)&hbrow[c0] = hv;
  }
}

// ---------------- launcher ----------------
extern "C" void kernel_launch(void* const* d_in, const int* in_sizes, int n_in,
                              void* d_out, int out_size, void* d_ws, size_t ws_size,
                              hipStream_t stream) {
  const float* x   = (const float*)d_in[0];
  const float* xm  = (const float*)d_in[1];
  const float* Wq  = (const float*)d_in[2];
  const float* bq  = (const float*)d_in[3];
  const float* Wk  = (const float*)d_in[4];
  const float* bk  = (const float*)d_in[5];
  const float* Wv  = (const float*)d_in[6];
  const float* bv  = (const float*)d_in[7];
  const float* Wo  = (const float*)d_in[8];
  const float* bo  = (const float*)d_in[9];
  const float* erk = (const float*)d_in[10];
  const float* erv = (const float*)d_in[11];
  const float* n1g = (const float*)d_in[12];
  const float* n1b = (const float*)d_in[13];
  const float* n2g = (const float*)d_in[14];
  const float* n2b = (const float*)d_in[15];
  const float* fw1 = (const float*)d_in[16];
  const float* fb1 = (const float*)d_in[17];
  const float* fw2 = (const float*)d_in[18];
  const float* fb2 = (const float*)d_in[19];

  char* ws = (char*)d_ws;
  f16*   WQKV = (f16*)(ws + WQKV_OFF);
  f16*   WOb  = (f16*)(ws + WO_OFF);
  f16*   W1b  = (f16*)(ws + W1_OFF);
  f16*   W2b  = (f16*)(ws + W2_OFF);
  float* BQKV = (float*)(ws + BQKV_OFF);
  float* Hb   = (float*)(ws + H_OFF);
  f16*   HB1  = (f16*)(ws + HB1_OFF);
  f16*   HB2  = (f16*)(ws + HB2_OFF);
  f16*   Y1B  = (f16*)(ws + Y1B_OFF);
  f16*   QB   = (f16*)(ws + QB_OFF);
  f16*   KB   = (f16*)(ws + KB_OFF);
  f16*   VT   = (f16*)(ws + VT_OFF);
  f16*   AO   = (f16*)(ws + AO_OFF);
  float* S    = (float*)(ws + S_OFF);
  f16*   P    = (f16*)(ws + P_OFF);
  float* RV   = (float*)(ws + RV_OFF);
  float* TMP  = (float*)(ws + TMP_OFF);

  zero_pads<<<128, 256, 0, stream>>>(HB1, HB2, Y1B);
  prep_in<<<dim3(16, 32, 4), dim3(32, 8), 0, stream>>>(x, xm, Hb, HB1);

  for (int l = 0; l < Ln; l++) {
    conv_wqkv<<<12288, 256, 0, stream>>>(Wq + (size_t)l * 1048576, Wk + (size_t)l * 1048576,
                                         Wv + (size_t)l * 1048576, bq + l * 1024,
                                         bk + l * 1024, bv + l * 1024, WQKV, BQKV);
    conv_cast<<<4096, 256, 0, stream>>>(Wo + (size_t)l * 1048576, WOb, 1048576);
    conv_w3<<<16384, 256, 0, stream>>>(fw1 + (size_t)l * 12582912, W1b, 10);
    conv_w3<<<16384, 256, 0, stream>>>(fw2 + (size_t)l * 12582912, W2b, 12);

    gemm_k<0><<<dim3(24, 16, 1), 256, 0, stream>>>(HB1, WQKV, QB, KB, VT, BQKV, nullptr, nullptr);
    gemm_k<1><<<dim3(4, 4, 64), 256, 0, stream>>>(QB, KB, S, nullptr, nullptr, nullptr, nullptr, nullptr);
    softmax_k<<<8192, 256, 0, stream>>>(S, P, QB, erk + l * 576, xm);
    relv_k<<<8192, 256, 0, stream>>>(P, erv + l * 576, RV);
    gemm_k<2><<<dim3(1, 4, 64), 256, 0, stream>>>(P, VT, AO, nullptr, nullptr, RV, nullptr, nullptr);
    gemm_k<3><<<dim3(16, 16, 1), 256, 0, stream>>>(AO, WOb, TMP, nullptr, nullptr, bo + l * 1024, Hb, nullptr);
    ln_k<1><<<512, 256, 0, stream>>>(TMP, n1g + l * 1024, n1b + l * 1024, xm, Hb, HB2);
    gemm_k<4><<<dim3(32, 16, 1), 256, 0, stream>>>(HB2, W1b, Y1B, nullptr, nullptr, fb1 + l * 4096, xm, nullptr);
    gemm_k<5><<<dim3(16, 16, 1), 256, 0, stream>>>(Y1B, W2b, TMP, nullptr, nullptr, fb2 + l * 1024, Hb, xm);
    ln_k<2><<<512, 256, 0, stream>>>(TMP, n2g + l * 1024, n2b + l * 1024, xm, Hb, HB1);
  }

  finish_out<<<dim3(16, 32, 4), dim3(32, 8), 0, stream>>>(Hb, xm, (float*)d_out);
}